// Round 1
// baseline (600.114 us; speedup 1.0000x reference)
//
#include <hip/hip_runtime.h>

// Problem: x(32,8,32,64,64) conv3d w(16,8,3,3,3) VALID -> (32,16,30,62,62),
// +conv_bias, /2, maxpool2 -> (32,16,15,31,31), mean(DHW), +bias, sum(C) -> (32)
// out[b] = (1/14415) * sum_{c,pd,ph,pw} [ (max8(conv) + cb[c]) * 0.5 ] + sum_c bias[c]

#define NWG 7680  // 32 b * 15 pd * 16 c

__global__ void bias_init_kernel(const float* __restrict__ bias, float* __restrict__ out) {
  int b = threadIdx.x;
  if (b < 32) {
    float s = 0.f;
#pragma unroll
    for (int c = 0; c < 16; ++c) s += bias[c];
    out[b] = s;  // d_out is poisoned 0xAA before every launch; init here
  }
}

__global__ __launch_bounds__(512, 4) void conv_fused_kernel(
    const float* __restrict__ x,
    const float* __restrict__ wgt,
    const float* __restrict__ cbias,
    float* __restrict__ out) {
  __shared__ float lds_x[4 * 64 * 64];  // 4 input d-planes of one channel: 64 KB
  __shared__ float lds_w[8 * 27];       // weights for this block's output channel
  __shared__ float redbuf[8];

  // XCD-aware inverse swizzle: consecutive logical blocks (sharing the x-slab
  // across the 16 output channels) land on the same XCD's L2. nwg%8==0 -> bijective.
  const int j = blockIdx.x;
  const int L = (j & 7) * (NWG / 8) + (j >> 3);
  const int c  = L & 15;        // output channel (fastest -> 16 consecutive share x)
  const int bp = L >> 4;
  const int pd = bp % 15;       // pooled depth index
  const int b  = bp / 15;       // batch

  const int tid = threadIdx.x;
  if (tid < 216) lds_w[tid] = wgt[c * 216 + tid];  // [ci][kd][kh][kw]

  // thread -> (pw, 2 consecutive ph)
  const int pw   = tid & 31;          // 0..31 (31 invalid, masked)
  const int ph0  = (tid >> 5) * 2;    // 0,2,...,30
  const int pw_c = min(pw, 30);       // clamp: garbage reads only feed masked outputs
  int rowoff[6];
#pragma unroll
  for (int r = 0; r < 6; ++r) rowoff[r] = min(2 * ph0 + r, 63) * 64 + 2 * pw_c;

  const float* xb = x + ((size_t)(b * 8) * 32 + 2 * pd) * 4096;
  const int wave = tid >> 6;
  const int lane = tid & 63;

  float acc[2][8];  // [po][dd*4+hh*2+ww] conv accumulators, persist across ci
#pragma unroll
  for (int po = 0; po < 2; ++po)
#pragma unroll
    for (int k = 0; k < 8; ++k) acc[po][k] = 0.f;

  for (int ci = 0; ci < 8; ++ci) {
    const float* src = xb + (size_t)ci * 32 * 4096;
    __syncthreads();  // previous compute done before overwriting lds_x
    // stage 4 contiguous d-planes (65536 B) via async global->LDS, 16 B/lane
#pragma unroll
    for (int i = 0; i < 8; ++i) {
      const int chunk = i * 8 + wave;  // 1 KB chunks, wave-uniform LDS base
      __builtin_amdgcn_global_load_lds(
          (__attribute__((address_space(1))) void*)(src + chunk * 256 + lane * 4),
          (__attribute__((address_space(3))) void*)(lds_x + chunk * 256),
          16, 0, 0);
    }
    __syncthreads();  // vmcnt(0) drained by compiler before barrier

    float wv[27];
#pragma unroll
    for (int k = 0; k < 27; ++k) wv[k] = lds_w[ci * 27 + k];  // broadcast reads

#pragma unroll
    for (int kd = 0; kd < 4; ++kd) {
      // this thread's 6 input rows x 4 w values for plane kd (two ds_read_b64 each)
      float xv[6][4];
#pragma unroll
      for (int r = 0; r < 6; ++r) {
        const float* p = &lds_x[kd * 4096 + rowoff[r]];
        float2 lo = *(const float2*)p;
        float2 hi = *(const float2*)(p + 2);
        xv[r][0] = lo.x; xv[r][1] = lo.y; xv[r][2] = hi.x; xv[r][3] = hi.y;
      }
#pragma unroll
      for (int dd = 0; dd < 2; ++dd) {
        const int kdd = kd - dd;  // weight d-index contributing from plane kd
        if (kdd >= 0 && kdd <= 2) {
#pragma unroll
          for (int po = 0; po < 2; ++po)
#pragma unroll
            for (int hh = 0; hh < 2; ++hh)
#pragma unroll
              for (int ww = 0; ww < 2; ++ww) {
                float s = acc[po][dd * 4 + hh * 2 + ww];
#pragma unroll
                for (int kh = 0; kh < 3; ++kh)
#pragma unroll
                  for (int kw = 0; kw < 3; ++kw)
                    s = fmaf(wv[kdd * 9 + kh * 3 + kw],
                             xv[2 * po + hh + kh][ww + kw], s);
                acc[po][dd * 4 + hh * 2 + ww] = s;
              }
        }
      }
    }
  }

  // epilogue: maxpool over the 8 conv values, +cb, /2, masked partial sum
  const float cbv = cbias[c];
  float partial = 0.f;
#pragma unroll
  for (int po = 0; po < 2; ++po) {
    const int ph = ph0 + po;
    if (ph < 31 && pw < 31) {
      float m = acc[po][0];
#pragma unroll
      for (int k = 1; k < 8; ++k) m = fmaxf(m, acc[po][k]);
      partial += (m + cbv) * 0.5f;
    }
  }
  // wave reduce (64 lanes) then block reduce then one atomic per block
#pragma unroll
  for (int off = 32; off > 0; off >>= 1) partial += __shfl_down(partial, off, 64);
  if (lane == 0) redbuf[wave] = partial;
  __syncthreads();
  if (tid == 0) {
    float s = 0.f;
#pragma unroll
    for (int i = 0; i < 8; ++i) s += redbuf[i];
    atomicAdd(&out[b], s * (1.0f / 14415.0f));
  }
}

extern "C" void kernel_launch(void* const* d_in, const int* in_sizes, int n_in,
                              void* d_out, int out_size, void* d_ws, size_t ws_size,
                              hipStream_t stream) {
  const float* x     = (const float*)d_in[0];
  const float* wgt   = (const float*)d_in[1];
  const float* cb    = (const float*)d_in[2];
  const float* bias  = (const float*)d_in[3];
  float* out = (float*)d_out;
  bias_init_kernel<<<1, 32, 0, stream>>>(bias, out);
  conv_fused_kernel<<<NWG, 512, 0, stream>>>(x, wgt, cb, out);
}

// Round 2
// 302.006 us; speedup vs baseline: 1.9871x; 1.9871x over previous
//
#include <hip/hip_runtime.h>

// out[b] = (1/14415) * sum_{c,pd,ph,pw} [ (max8(conv3d(x,w)[b,c,...]) + cb[c]) * 0.5 ] + sum_c bias[c]
// Conv as implicit GEMM on f16 MFMA: per (kd,kh) tap, K=32 = (kw 0..3 pad) x (ci 0..7),
// M=16 conv-w positions, N=16 output channels. x staged fp16 in LDS [d][h][w][ci].

typedef _Float16 half8 __attribute__((ext_vector_type(8)));
typedef _Float16 half2t __attribute__((ext_vector_type(2)));
typedef float float4t __attribute__((ext_vector_type(4)));
typedef unsigned long ulong2t __attribute__((ext_vector_type(2)));

#define NB 1920  // 32 b * 15 pd * 4 h-chunks

__global__ void bias_init_kernel(const float* __restrict__ bias, float* __restrict__ out) {
  int b = threadIdx.x;
  if (b < 32) {
    float s = 0.f;
#pragma unroll
    for (int c = 0; c < 16; ++c) s += bias[c];
    out[b] = s;
  }
}

__global__ __launch_bounds__(512, 4) void conv_mfma_kernel(
    const float* __restrict__ x,
    const float* __restrict__ wgt,
    const float* __restrict__ cbias,
    float* __restrict__ out) {
  // 4 d-planes x 18 h-rows x 68 w (64 + 3 tap reach + 1 pad) x 8 ci, fp16 = 76.5 KB
  __shared__ _Float16 xs[4][18][68][8];
  __shared__ float redbuf[8];

  const int bid = blockIdx.x;
  const int hc = bid & 3;           // pooled-h chunk (8 hp each, last has 7 valid)
  const int pd = (bid >> 2) % 15;
  const int b  = bid / 60;
  const int hb = hc * 8;

  const int tid  = threadIdx.x;
  const int lane = tid & 63;
  const int wave = tid >> 6;
  const int g    = lane >> 4;       // lane group 0..3
  const int m16  = lane & 15;

  // ---- B fragments: k = kw*8 + ci; lane l, half h2, elem j -> ci=4*(g&1)+j, kw=(g>>1)+2*h2
  // Same (lane,elem)->k map is used for A, so any k relabeling cancels in the contraction.
  half8 bfrag[9];
  {
    const int cib  = 4 * (g & 1);
    const int kwlo = g >> 1;
#pragma unroll
    for (int kd = 0; kd < 3; ++kd)
#pragma unroll
      for (int kh = 0; kh < 3; ++kh) {
        half8 f;
#pragma unroll
        for (int h2 = 0; h2 < 2; ++h2) {
          const int kw = kwlo + 2 * h2;
#pragma unroll
          for (int j = 0; j < 4; ++j) {
            float v = (kw < 3) ? wgt[(((m16 * 8 + cib + j) * 3 + kd) * 3 + kh) * 3 + kw] : 0.f;
            f[h2 * 4 + j] = (_Float16)v;
          }
        }
        bfrag[kd * 3 + kh] = f;
      }
  }

  // ---- zero the w-pad (cols 64..67): garbage there must be FINITE (0 * NaN = NaN!)
  if (tid < 288) {  // 4d * 18h * 4w
    const int w4 = tid & 3, h = (tid >> 2) % 18, dpl = tid / 72;
    *reinterpret_cast<float4t*>(&xs[dpl][h][64 + w4][0]) = float4t{0.f, 0.f, 0.f, 0.f};
  }

  // ---- stage x fp32 -> fp16 into LDS: 8ci x 4d x 18h x 64w
  {
    const float* xb = x + (size_t)b * 8 * 32 * 4096;
#pragma unroll
    for (int it = 0; it < 18; ++it) {
      const int q   = tid + it * 512;   // quad = (2 w) x (2 ci)
      const int wp  = q & 31;
      const int cp  = (q >> 5) & 3;
      const int row = q >> 7;           // 0..71
      const int h   = row % 18;
      const int dpl = row / 18;
      const int hin = min(2 * hb + h, 63);
      const int d   = 2 * pd + dpl;
      const float* p0 = xb + ((size_t)(2 * cp) * 32 + d) * 4096 + hin * 64 + 2 * wp;
      const float* p1 = p0 + 32 * 4096;  // next ci
      const float2 a0 = *(const float2*)p0;
      const float2 a1 = *(const float2*)p1;
      half2t v0, v1;
      v0[0] = (_Float16)a0.x; v0[1] = (_Float16)a1.x;   // (w, ci), (w, ci+1)
      v1[0] = (_Float16)a0.y; v1[1] = (_Float16)a1.y;
      *reinterpret_cast<half2t*>(&xs[dpl][h][2 * wp][2 * cp])     = v0;
      *reinterpret_cast<half2t*>(&xs[dpl][h][2 * wp + 1][2 * cp]) = v1;
    }
  }
  __syncthreads();

  // ---- compute: 32 wave-tasks = 8 hp x 4 w-tiles; each task 9 taps x 4 C-tiles (2d x 2h)
  float sumv = 0.f;
  const float cbv = cbias[m16];

#pragma unroll
  for (int ti = 0; ti < 4; ++ti) {
    const int task = wave + ti * 8;
    const int hpl  = task & 7;
    const int wt   = task >> 3;
    const int hp   = hb + hpl;
    if (hp <= 30) {
      const int w0 = wt * 16;
      // lane A base: w slot = w0 + m + kw_lo, ci-half byte = (g&1)*8; half1 = +32 B (kw+2)
      const char* abase = (const char*)xs + 2 * hpl * (68 * 16)
                        + (w0 + m16 + (g >> 1)) * 16 + (g & 1) * 8;
      float4t acc[2][2] = {{{0.f,0.f,0.f,0.f},{0.f,0.f,0.f,0.f}},
                           {{0.f,0.f,0.f,0.f},{0.f,0.f,0.f,0.f}}};
#pragma unroll
      for (int kd = 0; kd < 3; ++kd)
#pragma unroll
        for (int kh = 0; kh < 3; ++kh) {
          const half8 bv = bfrag[kd * 3 + kh];
#pragma unroll
          for (int dd = 0; dd < 2; ++dd)
#pragma unroll
            for (int hh = 0; hh < 2; ++hh) {
              const char* p = abase + ((dd + kd) * 18 + hh + kh) * (68 * 16);
              union { ulong2t u; half8 h; } af;
              af.u.x = *(const unsigned long*)p;         // k half0 (kw_lo)
              af.u.y = *(const unsigned long*)(p + 32);  // k half1 (kw_lo+2)
              acc[dd][hh] = __builtin_amdgcn_mfma_f32_16x16x32_f16(
                  af.h, bv, acc[dd][hh], 0, 0, 0);
            }
        }
      // epilogue: lane holds channel n=m16, rows m = g*4+reg = 4 consecutive conv-w.
      // maxpool: w-pairs = reg pairs; h-pair and d-pair = the 4 C-tiles.
#pragma unroll
      for (int p = 0; p < 2; ++p) {
        float v = acc[0][0][2 * p];
        v = fmaxf(v, acc[0][0][2 * p + 1]);
        v = fmaxf(v, acc[0][1][2 * p]); v = fmaxf(v, acc[0][1][2 * p + 1]);
        v = fmaxf(v, acc[1][0][2 * p]); v = fmaxf(v, acc[1][0][2 * p + 1]);
        v = fmaxf(v, acc[1][1][2 * p]); v = fmaxf(v, acc[1][1][2 * p + 1]);
        const int pw = (w0 >> 1) + g * 2 + p;
        if (pw <= 30) sumv += (v + cbv) * 0.5f;
      }
    }
  }

  // ---- reduce: sum over lanes (covers channels + w), waves, then one atomic
#pragma unroll
  for (int off = 32; off; off >>= 1) sumv += __shfl_down(sumv, off, 64);
  if (lane == 0) redbuf[wave] = sumv;
  __syncthreads();
  if (tid == 0) {
    float s = 0.f;
#pragma unroll
    for (int i = 0; i < 8; ++i) s += redbuf[i];
    atomicAdd(&out[b], s * (1.0f / 14415.0f));
  }
}

extern "C" void kernel_launch(void* const* d_in, const int* in_sizes, int n_in,
                              void* d_out, int out_size, void* d_ws, size_t ws_size,
                              hipStream_t stream) {
  const float* x    = (const float*)d_in[0];
  const float* wgt  = (const float*)d_in[1];
  const float* cb   = (const float*)d_in[2];
  const float* bias = (const float*)d_in[3];
  float* out = (float*)d_out;
  bias_init_kernel<<<1, 32, 0, stream>>>(bias, out);
  conv_mfma_kernel<<<NB, 512, 0, stream>>>(x, wgt, cb, out);
}

// Round 3
// 220.484 us; speedup vs baseline: 2.7218x; 1.3697x over previous
//
#include <hip/hip_runtime.h>

// out[b] = (1/14415) * sum_{c,pd,ph,pw} [ (max8(conv3d(x,w)[b,c]) + cb[c]) * 0.5 ] + sum_c bias[c]
// Implicit-GEMM f16 MFMA conv. K = 32 = (kw-slot = lane-group g) x (ci = elem j);
// A-frag = ONE contiguous ds_read_b128 per (d,h) row; 16 distinct frags register-cached
// and reused across 36 MFMAs (taps x C-tiles). Verified C/D map: col=lane&15=channel,
// row=4*g+reg = conv-w (R2 passed end-to-end with this mapping).

typedef _Float16 half8 __attribute__((ext_vector_type(8)));
typedef float float4t __attribute__((ext_vector_type(4)));

#define NB 3840  // 32 b * 15 pd * 8 h-chunks (4 pooled rows each)

__global__ void bias_init_kernel(const float* __restrict__ bias, float* __restrict__ out) {
  int b = threadIdx.x;
  if (b < 32) {
    float s = 0.f;
#pragma unroll
    for (int c = 0; c < 16; ++c) s += bias[c];
    out[b] = s;  // d_out poisoned 0xAA before every launch
  }
}

// Pre-swizzle weights: wr[t=kd*3+kh][g][m16] = half8 of ci 0..7 at kw=g (g==3 -> 0 pad).
__global__ void wprep_kernel(const float* __restrict__ wgt, half8* __restrict__ wr) {
  const int tid = threadIdx.x;
  if (tid < 576) {
    const int t = tid / 64, r = tid & 63, g = r >> 4, m = r & 15;
    const int kd = t / 3, kh = t % 3;
    half8 f;
#pragma unroll
    for (int j = 0; j < 8; ++j)
      f[j] = (g < 3) ? (_Float16)wgt[(((m * 8 + j) * 3 + kd) * 3 + kh) * 3 + g]
                     : (_Float16)0.f;
    wr[tid] = f;
  }
}

__global__ __launch_bounds__(512, 6) void conv_mfma_kernel(
    const float* __restrict__ x,
    const half8* __restrict__ wr,
    const float* __restrict__ cbias,
    float* __restrict__ out) {
  // 4 d-planes x 10 h-rows x 68 w-slots (64 + 3 reach + 1 pad) x 8 ci fp16 = 43,520 B
  __shared__ _Float16 xs[4][10][68][8];
  __shared__ float redbuf[8];

  const int bid = blockIdx.x;
  const int hc = bid & 7;            // h-chunk: 4 pooled rows
  const int pd = (bid >> 3) % 15;
  const int b  = bid / 120;
  const int hb = hc * 4;

  const int tid  = threadIdx.x;
  const int lane = tid & 63;
  const int wave = tid >> 6;
  const int g    = lane >> 4;        // = kw slot (3 -> zero weights)
  const int m16  = lane & 15;

  // ---- B fragments: 9 coalesced 16-B loads from pre-swizzled weights
  half8 bfrag[9];
#pragma unroll
  for (int t = 0; t < 9; ++t) bfrag[t] = wr[t * 64 + lane];

  // ---- zero the w-pad (slots 64..67): must be FINITE (0 * NaN = NaN)
  if (tid < 160) {
    const int w4 = tid & 3, h = (tid >> 2) % 10, d = tid / 40;
    *reinterpret_cast<float4t*>(&xs[d][h][64 + w4][0]) = float4t{0.f, 0.f, 0.f, 0.f};
  }

  // ---- stage x: each thread = one w-slot (8 ci), 8 coalesced dword loads ->
  //      cvt -> ONE ds_write_b128 (consecutive 16 B per lane: conflict-free)
  {
    const float* xb = x + ((size_t)b * 8 * 32 + 2 * pd) * 4096;
#pragma unroll
    for (int it = 0; it < 5; ++it) {
      const int s   = tid + it * 512;   // 2560 w-slots
      const int w   = s & 63;
      const int row = s >> 6;           // 0..39
      const int h   = row % 10;
      const int d   = row / 10;
      const int hin = min(2 * hb + h, 63);  // clamped rows feed only dead outputs
      const float* p = xb + (size_t)d * 4096 + hin * 64 + w;
      half8 v;
#pragma unroll
      for (int ci = 0; ci < 8; ++ci) v[ci] = (_Float16)p[ci * 131072];
      *reinterpret_cast<half8*>(&xs[d][h][w][0]) = v;
    }
  }
  __syncthreads();

  // ---- compute: 16 tasks = 4 hp x 4 w-tiles, 2 per wave
  float sumv = 0.f;
  const float cbv = cbias[m16];

#pragma unroll
  for (int ti = 0; ti < 2; ++ti) {
    const int task = wave + ti * 8;
    const int hpl  = task & 3;
    const int wt   = task >> 2;
    const int hp   = hb + hpl;
    if (hp <= 30) {
      const int w0 = wt * 16;
      // A row (M) = m16; lane's k-chunk = kw g -> w slot w0 + m16 + g (<= 66 < 68)
      const char* abase = (const char*)xs
                        + ((2 * hpl) * 68 + w0 + m16 + g) * 16;
      // register-cache the 16 distinct (D,H) row-frags, reuse across 36 MFMAs
      half8 af[4][4];
#pragma unroll
      for (int D = 0; D < 4; ++D)
#pragma unroll
        for (int H = 0; H < 4; ++H)
          af[D][H] = *reinterpret_cast<const half8*>(abase + (D * 10 + H) * (68 * 16));

      float4t acc[2][2] = {{{0.f,0.f,0.f,0.f},{0.f,0.f,0.f,0.f}},
                           {{0.f,0.f,0.f,0.f},{0.f,0.f,0.f,0.f}}};
#pragma unroll
      for (int kd = 0; kd < 3; ++kd)
#pragma unroll
        for (int kh = 0; kh < 3; ++kh) {
          const half8 bv = bfrag[kd * 3 + kh];
#pragma unroll
          for (int dd = 0; dd < 2; ++dd)
#pragma unroll
            for (int hh = 0; hh < 2; ++hh)
              acc[dd][hh] = __builtin_amdgcn_mfma_f32_16x16x32_f16(
                  af[dd + kd][hh + kh], bv, acc[dd][hh], 0, 0, 0);
        }
      // epilogue: lane = channel m16; rows = 4g+reg = conv-w. maxpool:
      // w-pairs = reg pairs, h/d pairs = the 4 C-tiles.
#pragma unroll
      for (int p = 0; p < 2; ++p) {
        float v = acc[0][0][2 * p];
        v = fmaxf(v, acc[0][0][2 * p + 1]);
        v = fmaxf(v, acc[0][1][2 * p]); v = fmaxf(v, acc[0][1][2 * p + 1]);
        v = fmaxf(v, acc[1][0][2 * p]); v = fmaxf(v, acc[1][0][2 * p + 1]);
        v = fmaxf(v, acc[1][1][2 * p]); v = fmaxf(v, acc[1][1][2 * p + 1]);
        const int pw = 8 * wt + 2 * g + p;
        if (pw <= 30) sumv += (v + cbv) * 0.5f;
      }
    }
  }

  // ---- reduce: lanes (channels+w) -> waves -> one atomic per block
#pragma unroll
  for (int off = 32; off; off >>= 1) sumv += __shfl_down(sumv, off, 64);
  if (lane == 0) redbuf[wave] = sumv;
  __syncthreads();
  if (tid == 0) {
    float s = 0.f;
#pragma unroll
    for (int i = 0; i < 8; ++i) s += redbuf[i];
    atomicAdd(&out[b], s * (1.0f / 14415.0f));
  }
}

extern "C" void kernel_launch(void* const* d_in, const int* in_sizes, int n_in,
                              void* d_out, int out_size, void* d_ws, size_t ws_size,
                              hipStream_t stream) {
  const float* x    = (const float*)d_in[0];
  const float* wgt  = (const float*)d_in[1];
  const float* cb   = (const float*)d_in[2];
  const float* bias = (const float*)d_in[3];
  float* out = (float*)d_out;
  half8* wr  = (half8*)d_ws;  // 576 * 16 B = 9216 B
  bias_init_kernel<<<1, 32, 0, stream>>>(bias, out);
  wprep_kernel<<<1, 576, 0, stream>>>(wgt, wr);
  conv_mfma_kernel<<<NB, 512, 0, stream>>>(x, wr, cb, out);
}